// Round 9
// baseline (238.157 us; speedup 1.0000x reference)
//
#include <hip/hip_runtime.h>
#include <math.h>

#define NC   1000                 // NUM_CLASSES
#define NVEC 250                  // float4 chunks per row (1000/4)
#define WPB  4                    // waves per block (256 threads)
#define RPW  8                    // consecutive rows per wave, looped w/ prefetch
#define L2E  1.4426950408889634f  // log2(e)

typedef float v4f __attribute__((ext_vector_type(4)));

#if __has_builtin(__builtin_amdgcn_exp2f)
#define FAST_EXP2(x) __builtin_amdgcn_exp2f(x)   // v_exp_f32
#else
#define FAST_EXP2(x) exp2f(x)
#endif

#if __has_builtin(__builtin_amdgcn_rcpf)
#define FAST_RCP(x) __builtin_amdgcn_rcpf(x)     // v_rcp_f32
#else
#define FAST_RCP(x) (1.0f / (x))
#endif

struct Row { float4 c0, c1, c2, c3; };

__device__ __forceinline__ Row load_row(const float* __restrict__ in, int row,
                                        int lane, bool tail) {
    const float4* __restrict__ rp = (const float4*)(in + (size_t)row * NC);
    Row r;
    r.c0 = rp[lane];
    r.c1 = rp[lane + 64];
    r.c2 = rp[lane + 128];
    r.c3 = tail ? rp[lane + 192] : make_float4(0.f, 0.f, 0.f, 0.f);
    return r;
}

__device__ __forceinline__ void accum_chunk(const float4& c, float& sr, float& sa, float& sa2) {
    const float a0 = fabsf(c.x), a1 = fabsf(c.y), a2 = fabsf(c.z), a3 = fabsf(c.w);
    sr  += (c.x + c.y) + (c.z + c.w);
    sa  += (a0 + a1) + (a2 + a3);
    sa2 += (a0 * a0 + a1 * a1) + (a2 * a2 + a3 * a3);
}

__device__ __forceinline__ float elem(float x, float kx, float bx, float cn, float cS) {
    return fmaf(FAST_RCP(1.0f + FAST_EXP2(fmaf(fabsf(x), kx, bx))), fmaf(-cn, x, cS), x);
}

// reduce + stats + fused epilogue + nt store for one row held in registers
__device__ __forceinline__ void process_row(const Row& r, float* __restrict__ out,
                                            int row, int lane, bool tail) {
    float sr = 0.f, sa = 0.f, sa2 = 0.f;
    accum_chunk(r.c0, sr, sa, sa2);
    accum_chunk(r.c1, sr, sa, sa2);
    accum_chunk(r.c2, sr, sa, sa2);
    accum_chunk(r.c3, sr, sa, sa2);

    #pragma unroll
    for (int off = 32; off > 0; off >>= 1) {
        sr  += __shfl_xor(sr,  off, 64);
        sa  += __shfl_xor(sa,  off, 64);
        sa2 += __shfl_xor(sa2, off, 64);
    }

    const float mean    = sa * (1.0f / NC);
    const float var     = (sa2 - (float)NC * mean * mean) * (1.0f / (NC - 1));
    const float inv_std = rsqrtf(var);
    const float kx = -inv_std * L2E;
    const float bx =  mean * inv_std * L2E;
    const float c  = 1.0f / (NC - 1);
    const float cS = c * sr;
    const float cn = c * (float)NC;

    v4f* __restrict__ op = (v4f*)(out + (size_t)row * NC);
    {
        v4f o;
        o.x = elem(r.c0.x, kx, bx, cn, cS);
        o.y = elem(r.c0.y, kx, bx, cn, cS);
        o.z = elem(r.c0.z, kx, bx, cn, cS);
        o.w = elem(r.c0.w, kx, bx, cn, cS);
        __builtin_nontemporal_store(o, &op[lane]);
    }
    {
        v4f o;
        o.x = elem(r.c1.x, kx, bx, cn, cS);
        o.y = elem(r.c1.y, kx, bx, cn, cS);
        o.z = elem(r.c1.z, kx, bx, cn, cS);
        o.w = elem(r.c1.w, kx, bx, cn, cS);
        __builtin_nontemporal_store(o, &op[lane + 64]);
    }
    {
        v4f o;
        o.x = elem(r.c2.x, kx, bx, cn, cS);
        o.y = elem(r.c2.y, kx, bx, cn, cS);
        o.z = elem(r.c2.z, kx, bx, cn, cS);
        o.w = elem(r.c2.w, kx, bx, cn, cS);
        __builtin_nontemporal_store(o, &op[lane + 128]);
    }
    if (tail) {
        v4f o;
        o.x = elem(r.c3.x, kx, bx, cn, cS);
        o.y = elem(r.c3.y, kx, bx, cn, cS);
        o.z = elem(r.c3.z, kx, bx, cn, cS);
        o.w = elem(r.c3.w, kx, bx, cn, cS);
        __builtin_nontemporal_store(o, &op[lane + 192]);
    }
}

__global__ __launch_bounds__(256, 4)
void smooth_filter_kernel(const float* __restrict__ in,
                          float* __restrict__ out,
                          int rows) {
    const int  lane = threadIdx.x & 63;
    const bool tail = (lane < (NVEC - 192));          // lanes 0..57 own chunk 3
    const int  wid  = blockIdx.x * WPB + (threadIdx.x >> 6);
    const int  row0 = wid * RPW;
    if (row0 >= rows) return;                         // wave-uniform

    // steady-state pipeline: rotate prefetched row in, issue next row's 4
    // global_load_dwordx4 IMMEDIATELY, then do ~1000 cycles of reduce/
    // butterfly/epilogue on the current row — loads outstanding ~85% of
    // wave lifetime, per-wave phases decorrelate over the 8 iterations.
    if (row0 + RPW <= rows) {                         // full-tile fast path
        Row cur = load_row(in, row0, lane, tail);
        #pragma unroll
        for (int r = 0; r < RPW; ++r) {               // fully unrolled: static regs
            Row nxt;
            if (r + 1 < RPW) nxt = load_row(in, row0 + r + 1, lane, tail);
            process_row(cur, out, row0 + r, lane, tail);
            if (r + 1 < RPW) cur = nxt;
        }
    } else {                                          // guarded tail path
        Row cur = load_row(in, row0, lane, tail);
        #pragma unroll
        for (int r = 0; r < RPW; ++r) {
            const bool hn = (row0 + r + 1 < rows) && (r + 1 < RPW);
            Row nxt;
            if (hn) nxt = load_row(in, row0 + r + 1, lane, tail);
            process_row(cur, out, row0 + r, lane, tail);
            if (hn) cur = nxt; else break;
        }
    }
}

extern "C" void kernel_launch(void* const* d_in, const int* in_sizes, int n_in,
                              void* d_out, int out_size, void* d_ws, size_t ws_size,
                              hipStream_t stream) {
    const float* in  = (const float*)d_in[0];
    float*       out = (float*)d_out;
    const int rows   = in_sizes[0] / NC;                      // 32768
    const int rpb    = WPB * RPW;                             // 32 rows per block
    const int blocks = (rows + rpb - 1) / rpb;                // 1024
    smooth_filter_kernel<<<blocks, 256, 0, stream>>>(in, out, rows);
}

// Round 10
// 236.954 us; speedup vs baseline: 1.0051x; 1.0051x over previous
//
#include <hip/hip_runtime.h>
#include <math.h>

#define NC   1000                 // NUM_CLASSES
#define NVEC 250                  // float4 chunks per row (1000/4)
#define WPB  4                    // waves per block (256 threads)
#define RPW  4                    // consecutive rows per wave, looped w/ prefetch
#define L2E  1.4426950408889634f  // log2(e)

typedef float v4f __attribute__((ext_vector_type(4)));

#if __has_builtin(__builtin_amdgcn_exp2f)
#define FAST_EXP2(x) __builtin_amdgcn_exp2f(x)   // v_exp_f32
#else
#define FAST_EXP2(x) exp2f(x)
#endif

#if __has_builtin(__builtin_amdgcn_rcpf)
#define FAST_RCP(x) __builtin_amdgcn_rcpf(x)     // v_rcp_f32
#else
#define FAST_RCP(x) (1.0f / (x))
#endif

struct Row { float4 c0, c1, c2, c3; };

__device__ __forceinline__ Row load_row(const float* __restrict__ in, int row,
                                        int lane, bool tail) {
    const float4* __restrict__ rp = (const float4*)(in + (size_t)row * NC);
    Row r;
    r.c0 = rp[lane];
    r.c1 = rp[lane + 64];
    r.c2 = rp[lane + 128];
    r.c3 = tail ? rp[lane + 192] : make_float4(0.f, 0.f, 0.f, 0.f);
    return r;
}

__device__ __forceinline__ void accum_chunk(const float4& c, float& sr, float& sa, float& sa2) {
    const float a0 = fabsf(c.x), a1 = fabsf(c.y), a2 = fabsf(c.z), a3 = fabsf(c.w);
    sr  += (c.x + c.y) + (c.z + c.w);
    sa  += (a0 + a1) + (a2 + a3);
    sa2 += (a0 * a0 + a1 * a1) + (a2 * a2 + a3 * a3);
}

__device__ __forceinline__ float elem(float x, float kx, float bx, float cn, float cS) {
    return fmaf(FAST_RCP(1.0f + FAST_EXP2(fmaf(fabsf(x), kx, bx))), fmaf(-cn, x, cS), x);
}

// reduce + stats + fused epilogue + nt store for one row held in registers
__device__ __forceinline__ void process_row(const Row& r, float* __restrict__ out,
                                            int row, int lane, bool tail) {
    float sr = 0.f, sa = 0.f, sa2 = 0.f;
    accum_chunk(r.c0, sr, sa, sa2);
    accum_chunk(r.c1, sr, sa, sa2);
    accum_chunk(r.c2, sr, sa, sa2);
    accum_chunk(r.c3, sr, sa, sa2);

    #pragma unroll
    for (int off = 32; off > 0; off >>= 1) {
        sr  += __shfl_xor(sr,  off, 64);
        sa  += __shfl_xor(sa,  off, 64);
        sa2 += __shfl_xor(sa2, off, 64);
    }

    const float mean    = sa * (1.0f / NC);
    const float var     = (sa2 - (float)NC * mean * mean) * (1.0f / (NC - 1));
    const float inv_std = rsqrtf(var);
    const float kx = -inv_std * L2E;
    const float bx =  mean * inv_std * L2E;
    const float c  = 1.0f / (NC - 1);
    const float cS = c * sr;
    const float cn = c * (float)NC;

    v4f* __restrict__ op = (v4f*)(out + (size_t)row * NC);
    {
        v4f o;
        o.x = elem(r.c0.x, kx, bx, cn, cS);
        o.y = elem(r.c0.y, kx, bx, cn, cS);
        o.z = elem(r.c0.z, kx, bx, cn, cS);
        o.w = elem(r.c0.w, kx, bx, cn, cS);
        __builtin_nontemporal_store(o, &op[lane]);
    }
    {
        v4f o;
        o.x = elem(r.c1.x, kx, bx, cn, cS);
        o.y = elem(r.c1.y, kx, bx, cn, cS);
        o.z = elem(r.c1.z, kx, bx, cn, cS);
        o.w = elem(r.c1.w, kx, bx, cn, cS);
        __builtin_nontemporal_store(o, &op[lane + 64]);
    }
    {
        v4f o;
        o.x = elem(r.c2.x, kx, bx, cn, cS);
        o.y = elem(r.c2.y, kx, bx, cn, cS);
        o.z = elem(r.c2.z, kx, bx, cn, cS);
        o.w = elem(r.c2.w, kx, bx, cn, cS);
        __builtin_nontemporal_store(o, &op[lane + 128]);
    }
    if (tail) {
        v4f o;
        o.x = elem(r.c3.x, kx, bx, cn, cS);
        o.y = elem(r.c3.y, kx, bx, cn, cS);
        o.z = elem(r.c3.z, kx, bx, cn, cS);
        o.w = elem(r.c3.w, kx, bx, cn, cS);
        __builtin_nontemporal_store(o, &op[lane + 192]);
    }
}

__global__ __launch_bounds__(256, 8)   // 8 waves/EU -> 32 waves/CU; caps VGPR at 64
void smooth_filter_kernel(const float* __restrict__ in,
                          float* __restrict__ out,
                          int rows) {
    const int  lane = threadIdx.x & 63;
    const bool tail = (lane < (NVEC - 192));          // lanes 0..57 own chunk 3
    const int  wid  = blockIdx.x * WPB + (threadIdx.x >> 6);
    const int  row0 = wid * RPW;
    if (row0 >= rows) return;                         // wave-uniform

    // depth-1 prefetch pipeline at FULL occupancy: 2048 blocks = 8 blocks/CU
    // = 32 waves/CU resident (VGPR <= 64 tier). Each wave keeps ~4 KB in
    // flight ~70-85% of its lifetime; aggregate outstanding bytes/CU ~3x R9.
    if (row0 + RPW <= rows) {                         // full-tile fast path
        Row cur = load_row(in, row0, lane, tail);
        #pragma unroll
        for (int r = 0; r < RPW; ++r) {               // fully unrolled: static regs
            Row nxt;
            if (r + 1 < RPW) nxt = load_row(in, row0 + r + 1, lane, tail);
            process_row(cur, out, row0 + r, lane, tail);
            if (r + 1 < RPW) cur = nxt;
        }
    } else {                                          // guarded tail path
        Row cur = load_row(in, row0, lane, tail);
        #pragma unroll
        for (int r = 0; r < RPW; ++r) {
            const bool hn = (row0 + r + 1 < rows) && (r + 1 < RPW);
            Row nxt;
            if (hn) nxt = load_row(in, row0 + r + 1, lane, tail);
            process_row(cur, out, row0 + r, lane, tail);
            if (hn) cur = nxt; else break;
        }
    }
}

extern "C" void kernel_launch(void* const* d_in, const int* in_sizes, int n_in,
                              void* d_out, int out_size, void* d_ws, size_t ws_size,
                              hipStream_t stream) {
    const float* in  = (const float*)d_in[0];
    float*       out = (float*)d_out;
    const int rows   = in_sizes[0] / NC;                      // 32768
    const int rpb    = WPB * RPW;                             // 16 rows per block
    const int blocks = (rows + rpb - 1) / rpb;                // 2048 -> 8 blocks/CU
    smooth_filter_kernel<<<blocks, 256, 0, stream>>>(in, out, rows);
}